// Round 6
// baseline (129.232 us; speedup 1.0000x reference)
//
#include <hip/hip_runtime.h>
#include <math.h>

#define EMB 512
#define NM 5
#define HID 64
#define NQ 2048
#define NP 256

// ws layout (floats)
#define A_OFF 0
#define A_FLOATS (NM * NQ * HID)          // A[m][q][h] = hq + b1
#define B_OFF A_FLOATS                    // B[m][h/4][p][h%4] = hp

#define XPAD 68                            // floats per row in LDS (272B = 17x16B)

// ---------------------------------------------------------------------------
// Kernel 1: phase-1 GEMM. lane = row, h via wave => W1 wave-uniform (scalar
// path, no transpose). X staged in LDS: 64-d double-buffered chunks, pad-68
// rows -> ds_read_b128 at 8-phase minimum serialization. Register prefetch:
// chunk c+1 global loads issue BEFORE the FMA loop, LDS store AFTER it, so
// the vmcnt wait is hidden behind ~290 VALU cycles.
__global__ __launch_bounds__(256) void gemmAB(const float* __restrict__ Q,
                                              const float* __restrict__ P,
                                              const float* __restrict__ W1,
                                              const float* __restrict__ b1,
                                              float* __restrict__ A,
                                              float* __restrict__ Bv) {
    __shared__ float xs[2][64 * XPAD];
    int tid  = threadIdx.x;
    int lane = tid & 63;
    int hg   = blockIdx.x & 3;
    int m    = (blockIdx.x >> 2) % 5;
    int rb   = blockIdx.x / 20;
    int h0   = __builtin_amdgcn_readfirstlane(hg * 16 + (tid >> 6) * 4);
    bool isQ = rb < 32;
    const float* X  = isQ ? (Q + (size_t)rb * 64 * EMB)
                          : (P + (size_t)(rb - 32) * 64 * EMB);
    const float* Wr = W1 + ((size_t)m * 64 + h0) * 1024 + (isQ ? 0 : EMB);

    int row_l = tid >> 4;          // 0..15 (4 passes of +16)
    int dl4   = (tid & 15) * 4;    // float offset within 64-d chunk

#define LDX(K, DB) (*(const float4*)&X[(size_t)(row_l + (K)*16) * EMB + (DB) + dl4])
#define STX(BUF, K, V) (*(float4*)&xs[BUF][(row_l + (K)*16) * XPAD + dl4] = (V))

    // prologue: stage chunk 0
    {
        float4 v0 = LDX(0, 0), v1 = LDX(1, 0), v2 = LDX(2, 0), v3 = LDX(3, 0);
        STX(0, 0, v0); STX(0, 1, v1); STX(0, 2, v2); STX(0, 3, v3);
    }
    __syncthreads();

    float a0 = 0, a1 = 0, a2 = 0, a3 = 0;
#pragma unroll 1
    for (int c = 0; c < 8; ++c) {
        float4 n0, n1, n2, n3;
        if (c < 7) {                       // issue prefetch, no wait yet
            int db = (c + 1) * 64;
            n0 = LDX(0, db); n1 = LDX(1, db); n2 = LDX(2, db); n3 = LDX(3, db);
        }
        const float* xl = &xs[c & 1][lane * XPAD];
        const float* wc = Wr + c * 64;     // wave-uniform -> s_load
#pragma unroll
        for (int d4 = 0; d4 < 16; ++d4) {
            float4 x = *(const float4*)&xl[d4 * 4];   // ds_read_b128
            const float* wd = wc + d4 * 4;
            a0 = fmaf(x.x, wd[0],      a0); a0 = fmaf(x.y, wd[1],      a0);
            a0 = fmaf(x.z, wd[2],      a0); a0 = fmaf(x.w, wd[3],      a0);
            a1 = fmaf(x.x, wd[1024+0], a1); a1 = fmaf(x.y, wd[1024+1], a1);
            a1 = fmaf(x.z, wd[1024+2], a1); a1 = fmaf(x.w, wd[1024+3], a1);
            a2 = fmaf(x.x, wd[2048+0], a2); a2 = fmaf(x.y, wd[2048+1], a2);
            a2 = fmaf(x.z, wd[2048+2], a2); a2 = fmaf(x.w, wd[2048+3], a2);
            a3 = fmaf(x.x, wd[3072+0], a3); a3 = fmaf(x.y, wd[3072+1], a3);
            a3 = fmaf(x.z, wd[3072+2], a3); a3 = fmaf(x.w, wd[3072+3], a3);
        }
        if (c < 7) {                       // vmcnt wait lands here, post-FMA
            int nb = (c & 1) ^ 1;
            STX(nb, 0, n0); STX(nb, 1, n1); STX(nb, 2, n2); STX(nb, 3, n3);
        }
        __syncthreads();
    }
#undef LDX
#undef STX

    if (isQ) {
        int q = rb * 64 + lane;
        float4 o = { a0 + b1[m * 64 + h0 + 0], a1 + b1[m * 64 + h0 + 1],
                     a2 + b1[m * 64 + h0 + 2], a3 + b1[m * 64 + h0 + 3] };
        *(float4*)&A[((size_t)m * NQ + q) * HID + h0] = o;
    } else {
        int p = (rb - 32) * 64 + lane;
        float4 o = { a0, a1, a2, a3 };
        *(float4*)&Bv[(((size_t)(m * 16) + (h0 >> 2)) * NP + p) * 4] = o;
    }
}

// ---------------------------------------------------------------------------
// Kernel 2: fused relu-ensemble + mean/std/exp (unchanged, known-good).
__global__ __launch_bounds__(256) void fused_main(const float* __restrict__ A,
                                                  const float* __restrict__ Bv,
                                                  const float* __restrict__ W2,
                                                  const float* __restrict__ b2,
                                                  float* __restrict__ out) {
    int p  = threadIdx.x;            // 0..255
    int q0 = blockIdx.x * 2;

    float s1a = 0, s2a = 0, s1b = 0, s2b = 0;
    const float4* Bq = (const float4*)Bv + p;

#pragma unroll 1
    for (int m = 0; m < NM; ++m) {
        const float4* bm = Bq + (size_t)m * 16 * NP;
        float4 B0 = bm[0*NP],  B1 = bm[1*NP],  B2 = bm[2*NP],  B3 = bm[3*NP];
        float4 B4 = bm[4*NP],  B5 = bm[5*NP],  B6 = bm[6*NP],  B7 = bm[7*NP];
        float4 B8 = bm[8*NP],  B9 = bm[9*NP],  B10= bm[10*NP], B11= bm[11*NP];
        float4 B12= bm[12*NP], B13= bm[13*NP], B14= bm[14*NP], B15= bm[15*NP];

        const float* Ar  = A + ((size_t)m * NQ + q0) * HID;   // block-uniform
        const float* Wp2 = W2 + m * HID;                      // block-uniform
        float oa = 0.f, ob = 0.f;

#define HSTEP(BF, H0) { \
        float wa=Wp2[H0+0], wb=Wp2[H0+1], wc=Wp2[H0+2], wd=Wp2[H0+3]; \
        oa = fmaf(fmaxf(Ar[H0+0]    + BF.x, 0.f), wa, oa); \
        oa = fmaf(fmaxf(Ar[H0+1]    + BF.y, 0.f), wb, oa); \
        oa = fmaf(fmaxf(Ar[H0+2]    + BF.z, 0.f), wc, oa); \
        oa = fmaf(fmaxf(Ar[H0+3]    + BF.w, 0.f), wd, oa); \
        ob = fmaf(fmaxf(Ar[64+H0+0] + BF.x, 0.f), wa, ob); \
        ob = fmaf(fmaxf(Ar[64+H0+1] + BF.y, 0.f), wb, ob); \
        ob = fmaf(fmaxf(Ar[64+H0+2] + BF.z, 0.f), wc, ob); \
        ob = fmaf(fmaxf(Ar[64+H0+3] + BF.w, 0.f), wd, ob); }

        HSTEP(B0,  0)  HSTEP(B1,  4)  HSTEP(B2,  8)  HSTEP(B3, 12)
        HSTEP(B4, 16)  HSTEP(B5, 20)  HSTEP(B6, 24)  HSTEP(B7, 28)
        HSTEP(B8, 32)  HSTEP(B9, 36)  HSTEP(B10,40)  HSTEP(B11,44)
        HSTEP(B12,48)  HSTEP(B13,52)  HSTEP(B14,56)  HSTEP(B15,60)
#undef HSTEP

        float bb = b2[m];
        float xa = oa + bb, xb = ob + bb;
        s1a += xa; s2a = fmaf(xa, xa, s2a);
        s1b += xb; s2b = fmaf(xb, xb, s2b);
    }

    {
        float mean = s1a * 0.2f;
        float var  = fmaxf((s2a - s1a * s1a * 0.2f) * 0.25f, 0.f);
        out[(size_t)q0 * NP + p] = mean * __expf(-sqrtf(var));
    }
    {
        float mean = s1b * 0.2f;
        float var  = fmaxf((s2b - s1b * s1b * 0.2f) * 0.25f, 0.f);
        out[(size_t)(q0 + 1) * NP + p] = mean * __expf(-sqrtf(var));
    }
}

// ---------------------------------------------------------------------------
extern "C" void kernel_launch(void* const* d_in, const int* in_sizes, int n_in,
                              void* d_out, int out_size, void* d_ws, size_t ws_size,
                              hipStream_t stream) {
    const float* Q  = (const float*)d_in[0];   // (2048, 512)
    const float* P  = (const float*)d_in[1];   // (256, 512)
    const float* W1 = (const float*)d_in[2];   // (5, 64, 1024)
    const float* b1 = (const float*)d_in[3];   // (5, 64)
    const float* W2 = (const float*)d_in[4];   // (5, 64)
    const float* b2 = (const float*)d_in[5];   // (5,)
    float* out = (float*)d_out;

    float* ws = (float*)d_ws;
    float* A  = ws + A_OFF;
    float* B  = ws + B_OFF;

    gemmAB<<<720, 256, 0, stream>>>(Q, P, W1, b1, A, B);
    fused_main<<<NQ / 2, 256, 0, stream>>>(A, B, W2, b2, out);
}

// Round 7
// 103.323 us; speedup vs baseline: 1.2508x; 1.2508x over previous
//
#include <hip/hip_runtime.h>
#include <math.h>

#define EMB 512
#define NM 5
#define HID 64
#define NQ 2048
#define NP 256
#define MH 320
#define NROWS 2304
#define KSPLIT 4
#define KC 128            // K per split
#define CD 32             // K per LDS chunk
#define RPAD 68           // padded row-dim in LDS

// ws layout (floats)
#define PART_OFF 0
#define PART_FLOATS (KSPLIT * NROWS * MH)      // part[kc][row][mh]
#define A_OFF (PART_OFF + PART_FLOATS)
#define A_FLOATS (NM * NQ * HID)               // A[m][q][h] = hq + b1
#define B_OFF (A_OFF + A_FLOATS)               // B[m][h/4][p][h%4] = hp

// ---------------------------------------------------------------------------
// Kernel 1: outer-product register-tile GEMM, K-split x4.
// Block: 64 rows x 64 h (one m), 16x16 threads, 4x4 acc per thread.
// X and W staged TRANSPOSED in LDS ([d][row], pad 68): inner loop is
// 2 ds_read_b128 + 16 v_fmac per d — no scalar loads in the hot loop.
__global__ __launch_bounds__(256) void gemm_partial(const float* __restrict__ Q,
                                                    const float* __restrict__ P,
                                                    const float* __restrict__ W1,
                                                    float* __restrict__ part) {
    __shared__ float xs[CD][RPAD];
    __shared__ float wsh[CD][RPAD];

    int tid = threadIdx.x;
    int kc  = blockIdx.x & 3;
    int rbm = blockIdx.x >> 2;          // 0..179
    int m   = rbm % 5;
    int rb  = rbm / 5;                  // 0..35
    int r0  = rb * 64;
    bool isQ = rb < 32;
    const float* Xb = isQ ? (Q + (size_t)r0 * EMB) : (P + (size_t)(r0 - NQ) * EMB);
    const float* Wb = W1 + (size_t)m * 64 * 1024 + (isQ ? 0 : EMB);

    int srow = tid >> 2;                // 0..63 : staging row (X) / h (W)
    int d4l  = tid & 3;                 // staging d4 slot

    int tx = tid & 15;                  // row group
    int ty = tid >> 4;                  // col (h) group
    float4 cr0 = {0,0,0,0}, cr1 = {0,0,0,0}, cr2 = {0,0,0,0}, cr3 = {0,0,0,0};

#pragma unroll 1
    for (int c = 0; c < KC / CD; ++c) {
        int d0 = kc * KC + c * CD;
        // stage X[64 rows][32 d] and W[64 h][32 d], transposed into LDS
        float4 x0 = *(const float4*)&Xb[(size_t)srow * EMB + d0 + d4l * 4];
        float4 x1 = *(const float4*)&Xb[(size_t)srow * EMB + d0 + d4l * 4 + 16];
        float4 w0 = *(const float4*)&Wb[(size_t)srow * 1024 + d0 + d4l * 4];
        float4 w1 = *(const float4*)&Wb[(size_t)srow * 1024 + d0 + d4l * 4 + 16];
        __syncthreads();                 // previous chunk's reads done
        int dl = d4l * 4;
        xs[dl + 0][srow] = x0.x;  xs[dl + 1][srow] = x0.y;
        xs[dl + 2][srow] = x0.z;  xs[dl + 3][srow] = x0.w;
        xs[dl + 16][srow] = x1.x; xs[dl + 17][srow] = x1.y;
        xs[dl + 18][srow] = x1.z; xs[dl + 19][srow] = x1.w;
        wsh[dl + 0][srow] = w0.x;  wsh[dl + 1][srow] = w0.y;
        wsh[dl + 2][srow] = w0.z;  wsh[dl + 3][srow] = w0.w;
        wsh[dl + 16][srow] = w1.x; wsh[dl + 17][srow] = w1.y;
        wsh[dl + 18][srow] = w1.z; wsh[dl + 19][srow] = w1.w;
        __syncthreads();

#pragma unroll
        for (int d = 0; d < CD; ++d) {
            float4 x4 = *(const float4*)&xs[d][tx * 4];   // 4 rows
            float4 w4 = *(const float4*)&wsh[d][ty * 4];  // 4 cols
            cr0.x = fmaf(x4.x, w4.x, cr0.x); cr0.y = fmaf(x4.x, w4.y, cr0.y);
            cr0.z = fmaf(x4.x, w4.z, cr0.z); cr0.w = fmaf(x4.x, w4.w, cr0.w);
            cr1.x = fmaf(x4.y, w4.x, cr1.x); cr1.y = fmaf(x4.y, w4.y, cr1.y);
            cr1.z = fmaf(x4.y, w4.z, cr1.z); cr1.w = fmaf(x4.y, w4.w, cr1.w);
            cr2.x = fmaf(x4.z, w4.x, cr2.x); cr2.y = fmaf(x4.z, w4.y, cr2.y);
            cr2.z = fmaf(x4.z, w4.z, cr2.z); cr2.w = fmaf(x4.z, w4.w, cr2.w);
            cr3.x = fmaf(x4.w, w4.x, cr3.x); cr3.y = fmaf(x4.w, w4.y, cr3.y);
            cr3.z = fmaf(x4.w, w4.z, cr3.z); cr3.w = fmaf(x4.w, w4.w, cr3.w);
        }
    }

    size_t col = (size_t)m * 64 + ty * 4;
    size_t base = ((size_t)kc * NROWS + r0 + tx * 4) * MH + col;
    *(float4*)&part[base + 0 * MH] = cr0;
    *(float4*)&part[base + 1 * MH] = cr1;
    *(float4*)&part[base + 2 * MH] = cr2;
    *(float4*)&part[base + 3 * MH] = cr3;
}

// ---------------------------------------------------------------------------
// Kernel 2: reduce K-split partials; route to A (+b1) and blocked B.
__global__ __launch_bounds__(320) void reduce_route(const float* __restrict__ part,
                                                    const float* __restrict__ b1,
                                                    float* __restrict__ A,
                                                    float* __restrict__ Bv) {
    int t = threadIdx.x;                // mh 0..319
    int row0 = blockIdx.x * 8;
    int m = t >> 6, h = t & 63;
    float bb = b1[t];
#pragma unroll
    for (int j = 0; j < 8; ++j) {
        int row = row0 + j;
        float s = 0.f;
#pragma unroll
        for (int kc = 0; kc < KSPLIT; ++kc)
            s += part[((size_t)kc * NROWS + row) * MH + t];
        if (row < NQ) {
            A[((size_t)m * NQ + row) * HID + h] = s + bb;
        } else {
            int p = row - NQ;
            Bv[(((size_t)(m * 16 + (h >> 2))) * NP + p) * 4 + (h & 3)] = s;
        }
    }
}

// ---------------------------------------------------------------------------
// Kernel 3: fused relu-ensemble + mean/std/exp (unchanged, known-good).
__global__ __launch_bounds__(256) void fused_main(const float* __restrict__ A,
                                                  const float* __restrict__ Bv,
                                                  const float* __restrict__ W2,
                                                  const float* __restrict__ b2,
                                                  float* __restrict__ out) {
    int p  = threadIdx.x;            // 0..255
    int q0 = blockIdx.x * 2;

    float s1a = 0, s2a = 0, s1b = 0, s2b = 0;
    const float4* Bq = (const float4*)Bv + p;

#pragma unroll 1
    for (int m = 0; m < NM; ++m) {
        const float4* bm = Bq + (size_t)m * 16 * NP;
        float4 B0 = bm[0*NP],  B1 = bm[1*NP],  B2 = bm[2*NP],  B3 = bm[3*NP];
        float4 B4 = bm[4*NP],  B5 = bm[5*NP],  B6 = bm[6*NP],  B7 = bm[7*NP];
        float4 B8 = bm[8*NP],  B9 = bm[9*NP],  B10= bm[10*NP], B11= bm[11*NP];
        float4 B12= bm[12*NP], B13= bm[13*NP], B14= bm[14*NP], B15= bm[15*NP];

        const float* Ar  = A + ((size_t)m * NQ + q0) * HID;   // block-uniform
        const float* Wp2 = W2 + m * HID;                      // block-uniform
        float oa = 0.f, ob = 0.f;

#define HSTEP(BF, H0) { \
        float wa=Wp2[H0+0], wb=Wp2[H0+1], wc=Wp2[H0+2], wd=Wp2[H0+3]; \
        oa = fmaf(fmaxf(Ar[H0+0]    + BF.x, 0.f), wa, oa); \
        oa = fmaf(fmaxf(Ar[H0+1]    + BF.y, 0.f), wb, oa); \
        oa = fmaf(fmaxf(Ar[H0+2]    + BF.z, 0.f), wc, oa); \
        oa = fmaf(fmaxf(Ar[H0+3]    + BF.w, 0.f), wd, oa); \
        ob = fmaf(fmaxf(Ar[64+H0+0] + BF.x, 0.f), wa, ob); \
        ob = fmaf(fmaxf(Ar[64+H0+1] + BF.y, 0.f), wb, ob); \
        ob = fmaf(fmaxf(Ar[64+H0+2] + BF.z, 0.f), wc, ob); \
        ob = fmaf(fmaxf(Ar[64+H0+3] + BF.w, 0.f), wd, ob); }

        HSTEP(B0,  0)  HSTEP(B1,  4)  HSTEP(B2,  8)  HSTEP(B3, 12)
        HSTEP(B4, 16)  HSTEP(B5, 20)  HSTEP(B6, 24)  HSTEP(B7, 28)
        HSTEP(B8, 32)  HSTEP(B9, 36)  HSTEP(B10,40)  HSTEP(B11,44)
        HSTEP(B12,48)  HSTEP(B13,52)  HSTEP(B14,56)  HSTEP(B15,60)
#undef HSTEP

        float bb = b2[m];
        float xa = oa + bb, xb = ob + bb;
        s1a += xa; s2a = fmaf(xa, xa, s2a);
        s1b += xb; s2b = fmaf(xb, xb, s2b);
    }

    {
        float mean = s1a * 0.2f;
        float var  = fmaxf((s2a - s1a * s1a * 0.2f) * 0.25f, 0.f);
        out[(size_t)q0 * NP + p] = mean * __expf(-sqrtf(var));
    }
    {
        float mean = s1b * 0.2f;
        float var  = fmaxf((s2b - s1b * s1b * 0.2f) * 0.25f, 0.f);
        out[(size_t)(q0 + 1) * NP + p] = mean * __expf(-sqrtf(var));
    }
}

// ---------------------------------------------------------------------------
extern "C" void kernel_launch(void* const* d_in, const int* in_sizes, int n_in,
                              void* d_out, int out_size, void* d_ws, size_t ws_size,
                              hipStream_t stream) {
    const float* Q  = (const float*)d_in[0];   // (2048, 512)
    const float* P  = (const float*)d_in[1];   // (256, 512)
    const float* W1 = (const float*)d_in[2];   // (5, 64, 1024)
    const float* b1 = (const float*)d_in[3];   // (5, 64)
    const float* W2 = (const float*)d_in[4];   // (5, 64)
    const float* b2 = (const float*)d_in[5];   // (5,)
    float* out = (float*)d_out;

    float* ws   = (float*)d_ws;
    float* part = ws + PART_OFF;
    float* A    = ws + A_OFF;
    float* B    = ws + B_OFF;

    gemm_partial<<<180 * KSPLIT, 256, 0, stream>>>(Q, P, W1, part);
    reduce_route<<<NROWS / 8, 320, 0, stream>>>(part, b1, A, B);
    fused_main<<<NQ / 2, 256, 0, stream>>>(A, B, W2, b2, out);
}

// Round 8
// 96.944 us; speedup vs baseline: 1.3331x; 1.0658x over previous
//
#include <hip/hip_runtime.h>
#include <math.h>

#define EMB 512
#define NM 5
#define HID 64
#define NQ 2048
#define NP 256

// ws layout (floats)
#define A_OFF 0
#define A_FLOATS (NM * NQ * HID)          // A[m][q][h] = hq + b1
#define B_OFF A_FLOATS                    // B[m][h/4][p][h%4] = hp

typedef __attribute__((ext_vector_type(8))) short short8;   // 8 bf16 = 4 VGPR
typedef __attribute__((ext_vector_type(4))) float floatx4;

#define LSTR 40                            // LDS row stride in shorts (80B, 16B-aligned)

__device__ inline unsigned short bfr(float f) {            // f32 -> bf16 RNE
    unsigned u = __float_as_uint(f);
    u += 0x7FFFu + ((u >> 16) & 1u);
    return (unsigned short)(u >> 16);
}

// ---------------------------------------------------------------------------
// Kernel 1: phase-1 GEMM via split-bf16 MFMA (hi/lo Ootomo; err ~2^-17).
// Block: 64 rows x 64 h (one m), 256 thr = 4 waves; wave w = rows [16w,16w+16),
// 4 col-tiles of 16x16, mfma_f32_16x16x32_bf16, K=512 in 16 steps.
// Verified layouts: A[m=lane&15][k=(lane>>4)*8+j]; C/D col=lane&15,
// row=(lane>>4)*4+reg. Writes A(+b1) / blocked-B directly (no reduce kernel).
__global__ __launch_bounds__(256) void gemm_mfma(const float* __restrict__ Q,
                                                 const float* __restrict__ P,
                                                 const float* __restrict__ W1,
                                                 const float* __restrict__ b1,
                                                 float* __restrict__ A,
                                                 float* __restrict__ Bv) {
    __shared__ short XH[64 * LSTR], XL[64 * LSTR], WH[64 * LSTR], WL[64 * LSTR];

    int tid  = threadIdx.x;
    int lane = tid & 63;
    int w    = tid >> 6;
    int m    = blockIdx.x % 5;
    int rb   = blockIdx.x / 5;            // 0..35
    int r0   = rb * 64;
    bool isQ = rb < 32;
    const float* Xb = isQ ? (Q + (size_t)r0 * EMB) : (P + (size_t)(r0 - NQ) * EMB);
    const float* Wb = W1 + (size_t)m * 64 * 1024 + (isQ ? 0 : EMB);

    int srow = tid >> 2;                  // 0..63 staging row
    int kq   = (tid & 3) * 8;             // k offset within 32-chunk

    floatx4 ac0 = {0,0,0,0}, ac1 = {0,0,0,0}, ac2 = {0,0,0,0}, ac3 = {0,0,0,0};

    const float* xg = Xb + (size_t)srow * EMB + kq;
    const float* wg = Wb + (size_t)srow * 1024 + kq;

    float4 xa = *(const float4*)&xg[0], xb = *(const float4*)&xg[4];
    float4 wa = *(const float4*)&wg[0], wb = *(const float4*)&wg[4];

    int aoff = (w * 16 + (lane & 15)) * LSTR + (lane >> 4) * 8;
    int boff0 = ((lane & 15)) * LSTR + (lane >> 4) * 8;

#pragma unroll 1
    for (int s = 0; s < 16; ++s) {
        // convert current staged f32 -> hi/lo bf16
        short8 xh, xl, wh, wl;
#define CNV(HS, LS, I, VAL) { unsigned short h_ = bfr(VAL); HS[I] = (short)h_; \
        float hf_ = __uint_as_float(((unsigned)h_) << 16); LS[I] = (short)bfr((VAL) - hf_); }
        CNV(xh, xl, 0, xa.x) CNV(xh, xl, 1, xa.y) CNV(xh, xl, 2, xa.z) CNV(xh, xl, 3, xa.w)
        CNV(xh, xl, 4, xb.x) CNV(xh, xl, 5, xb.y) CNV(xh, xl, 6, xb.z) CNV(xh, xl, 7, xb.w)
        CNV(wh, wl, 0, wa.x) CNV(wh, wl, 1, wa.y) CNV(wh, wl, 2, wa.z) CNV(wh, wl, 3, wa.w)
        CNV(wh, wl, 4, wb.x) CNV(wh, wl, 5, wb.y) CNV(wh, wl, 6, wb.z) CNV(wh, wl, 7, wb.w)
#undef CNV
        __syncthreads();                       // prior step's frag reads done
        *(short8*)&XH[srow * LSTR + kq] = xh;
        *(short8*)&XL[srow * LSTR + kq] = xl;
        *(short8*)&WH[srow * LSTR + kq] = wh;
        *(short8*)&WL[srow * LSTR + kq] = wl;
        if (s < 15) {                          // prefetch next chunk (overlaps MFMA)
            int ks = (s + 1) * 32;
            xa = *(const float4*)&xg[ks];  xb = *(const float4*)&xg[ks + 4];
            wa = *(const float4*)&wg[ks];  wb = *(const float4*)&wg[ks + 4];
        }
        __syncthreads();

        short8 Ahi = *(const short8*)&XH[aoff];
        short8 Alo = *(const short8*)&XL[aoff];
        short8 B0h = *(const short8*)&WH[boff0];
        short8 B0l = *(const short8*)&WL[boff0];
        short8 B1h = *(const short8*)&WH[boff0 + 16 * LSTR];
        short8 B1l = *(const short8*)&WL[boff0 + 16 * LSTR];
        short8 B2h = *(const short8*)&WH[boff0 + 32 * LSTR];
        short8 B2l = *(const short8*)&WL[boff0 + 32 * LSTR];
        short8 B3h = *(const short8*)&WH[boff0 + 48 * LSTR];
        short8 B3l = *(const short8*)&WL[boff0 + 48 * LSTR];

        ac0 = __builtin_amdgcn_mfma_f32_16x16x32_bf16(Ahi, B0l, ac0, 0, 0, 0);
        ac0 = __builtin_amdgcn_mfma_f32_16x16x32_bf16(Alo, B0h, ac0, 0, 0, 0);
        ac0 = __builtin_amdgcn_mfma_f32_16x16x32_bf16(Ahi, B0h, ac0, 0, 0, 0);
        ac1 = __builtin_amdgcn_mfma_f32_16x16x32_bf16(Ahi, B1l, ac1, 0, 0, 0);
        ac1 = __builtin_amdgcn_mfma_f32_16x16x32_bf16(Alo, B1h, ac1, 0, 0, 0);
        ac1 = __builtin_amdgcn_mfma_f32_16x16x32_bf16(Ahi, B1h, ac1, 0, 0, 0);
        ac2 = __builtin_amdgcn_mfma_f32_16x16x32_bf16(Ahi, B2l, ac2, 0, 0, 0);
        ac2 = __builtin_amdgcn_mfma_f32_16x16x32_bf16(Alo, B2h, ac2, 0, 0, 0);
        ac2 = __builtin_amdgcn_mfma_f32_16x16x32_bf16(Ahi, B2h, ac2, 0, 0, 0);
        ac3 = __builtin_amdgcn_mfma_f32_16x16x32_bf16(Ahi, B3l, ac3, 0, 0, 0);
        ac3 = __builtin_amdgcn_mfma_f32_16x16x32_bf16(Alo, B3h, ac3, 0, 0, 0);
        ac3 = __builtin_amdgcn_mfma_f32_16x16x32_bf16(Ahi, B3h, ac3, 0, 0, 0);
    }

    int col  = lane & 15;
    int rloc = w * 16 + (lane >> 4) * 4;       // + reg

    if (isQ) {
        int q = r0 + rloc;
#define WRQ(AC, CT) { int h = CT * 16 + col; float bb = b1[m * 64 + h]; \
        float* dst = &A[((size_t)m * NQ + q) * HID + h]; \
        dst[0*HID] = AC.x + bb; dst[1*HID] = AC.y + bb; \
        dst[2*HID] = AC.z + bb; dst[3*HID] = AC.w + bb; }
        WRQ(ac0, 0) WRQ(ac1, 1) WRQ(ac2, 2) WRQ(ac3, 3)
#undef WRQ
    } else {
        int p = r0 - NQ + rloc;
#define WRP(AC, CT) { int h = CT * 16 + col; \
        float* dst = &Bv[(((size_t)(m * 16 + (h >> 2))) * NP + p) * 4 + (h & 3)]; \
        dst[0*4] = AC.x; dst[1*4] = AC.y; dst[2*4] = AC.z; dst[3*4] = AC.w; }
        WRP(ac0, 0) WRP(ac1, 1) WRP(ac2, 2) WRP(ac3, 3)
#undef WRP
    }
}

// ---------------------------------------------------------------------------
// Kernel 2: fused relu-ensemble + mean/std/exp (unchanged, known-good).
__global__ __launch_bounds__(256) void fused_main(const float* __restrict__ A,
                                                  const float* __restrict__ Bv,
                                                  const float* __restrict__ W2,
                                                  const float* __restrict__ b2,
                                                  float* __restrict__ out) {
    int p  = threadIdx.x;            // 0..255
    int q0 = blockIdx.x * 2;

    float s1a = 0, s2a = 0, s1b = 0, s2b = 0;
    const float4* Bq = (const float4*)Bv + p;

#pragma unroll 1
    for (int m = 0; m < NM; ++m) {
        const float4* bm = Bq + (size_t)m * 16 * NP;
        float4 B0 = bm[0*NP],  B1 = bm[1*NP],  B2 = bm[2*NP],  B3 = bm[3*NP];
        float4 B4 = bm[4*NP],  B5 = bm[5*NP],  B6 = bm[6*NP],  B7 = bm[7*NP];
        float4 B8 = bm[8*NP],  B9 = bm[9*NP],  B10= bm[10*NP], B11= bm[11*NP];
        float4 B12= bm[12*NP], B13= bm[13*NP], B14= bm[14*NP], B15= bm[15*NP];

        const float* Ar  = A + ((size_t)m * NQ + q0) * HID;   // block-uniform
        const float* Wp2 = W2 + m * HID;                      // block-uniform
        float oa = 0.f, ob = 0.f;

#define HSTEP(BF, H0) { \
        float wa=Wp2[H0+0], wb=Wp2[H0+1], wc=Wp2[H0+2], wd=Wp2[H0+3]; \
        oa = fmaf(fmaxf(Ar[H0+0]    + BF.x, 0.f), wa, oa); \
        oa = fmaf(fmaxf(Ar[H0+1]    + BF.y, 0.f), wb, oa); \
        oa = fmaf(fmaxf(Ar[H0+2]    + BF.z, 0.f), wc, oa); \
        oa = fmaf(fmaxf(Ar[H0+3]    + BF.w, 0.f), wd, oa); \
        ob = fmaf(fmaxf(Ar[64+H0+0] + BF.x, 0.f), wa, ob); \
        ob = fmaf(fmaxf(Ar[64+H0+1] + BF.y, 0.f), wb, ob); \
        ob = fmaf(fmaxf(Ar[64+H0+2] + BF.z, 0.f), wc, ob); \
        ob = fmaf(fmaxf(Ar[64+H0+3] + BF.w, 0.f), wd, ob); }

        HSTEP(B0,  0)  HSTEP(B1,  4)  HSTEP(B2,  8)  HSTEP(B3, 12)
        HSTEP(B4, 16)  HSTEP(B5, 20)  HSTEP(B6, 24)  HSTEP(B7, 28)
        HSTEP(B8, 32)  HSTEP(B9, 36)  HSTEP(B10,40)  HSTEP(B11,44)
        HSTEP(B12,48)  HSTEP(B13,52)  HSTEP(B14,56)  HSTEP(B15,60)
#undef HSTEP

        float bb = b2[m];
        float xa = oa + bb, xb = ob + bb;
        s1a += xa; s2a = fmaf(xa, xa, s2a);
        s1b += xb; s2b = fmaf(xb, xb, s2b);
    }

    {
        float mean = s1a * 0.2f;
        float var  = fmaxf((s2a - s1a * s1a * 0.2f) * 0.25f, 0.f);
        out[(size_t)q0 * NP + p] = mean * __expf(-sqrtf(var));
    }
    {
        float mean = s1b * 0.2f;
        float var  = fmaxf((s2b - s1b * s1b * 0.2f) * 0.25f, 0.f);
        out[(size_t)(q0 + 1) * NP + p] = mean * __expf(-sqrtf(var));
    }
}

// ---------------------------------------------------------------------------
extern "C" void kernel_launch(void* const* d_in, const int* in_sizes, int n_in,
                              void* d_out, int out_size, void* d_ws, size_t ws_size,
                              hipStream_t stream) {
    const float* Q  = (const float*)d_in[0];   // (2048, 512)
    const float* P  = (const float*)d_in[1];   // (256, 512)
    const float* W1 = (const float*)d_in[2];   // (5, 64, 1024)
    const float* b1 = (const float*)d_in[3];   // (5, 64)
    const float* W2 = (const float*)d_in[4];   // (5, 64)
    const float* b2 = (const float*)d_in[5];   // (5,)
    float* out = (float*)d_out;

    float* ws = (float*)d_ws;
    float* A  = ws + A_OFF;
    float* B  = ws + B_OFF;

    gemm_mfma<<<180, 256, 0, stream>>>(Q, P, W1, b1, A, B);
    fused_main<<<NQ / 2, 256, 0, stream>>>(A, B, W2, b2, out);
}